// Round 8
// baseline (1483.145 us; speedup 1.0000x reference)
//
#include <hip/hip_runtime.h>
#include <hip/hip_bf16.h>
#include <type_traits>

// LSTMNet: B=1024, T=2048, H=64, NC=10, input_size=1.
// MFMA (16x16x32 bf16) split-bf16 (hi+lo) fp32 emulation. Verified structure:
//   grid = 64 blocks x 4 waves; block owns 16 batch rows; wave w owns units
//   [16w,16w+16), all 4 gates -> in-register LSTM update, one barrier/step.
// R6 post-mortem: VALUBusy/MfmaUtil normalize over 256 CUs but only 64 are
// active -> true VALUBusy ~59%: the kernel is VALU-ISSUE-bound (~495 instr x
// 2cyc/step), not barrier-bound. R7/R8: cut VALU issue.
//   1. t-loop unrolled x2 -> ping-pong indices compile-time, LDS addrs
//      loop-invariant (+imm offsets), no addr math per step.
//   2. bias/zero folded into MFMA C operand (persistent biasv/zerov regs)
//      -> no 32 acc-init movs per step.
//   3. h hi/lo split via packed v_cvt_pk_bf16_f32 (__float22bfloat162_rn)
//      -> ~12 instr instead of ~48.
// R8 fix: __hip_bfloat162 not trivially copyable -> extract bits with
// __builtin_memcpy instead of __builtin_bit_cast.

#define T_STEPS 2048
#define HID 64
#define NCLS 10
#define XCH 128   // x chunk length (steps)

typedef short bf16x8 __attribute__((ext_vector_type(8)));
typedef float f32x4 __attribute__((ext_vector_type(4)));

__device__ __forceinline__ float sigm(float x) {
    float e = __builtin_amdgcn_exp2f(-1.4426950408889634f * x);
    return __builtin_amdgcn_rcpf(1.0f + e);
}
__device__ __forceinline__ float tanh_f(float x) {
    float e = __builtin_amdgcn_exp2f(-2.8853900817779268f * x);
    return fmaf(2.0f, __builtin_amdgcn_rcpf(1.0f + e), -1.0f);
}
__device__ __forceinline__ unsigned short f2bf(float f) {  // RNE f32->bf16
    unsigned u = __builtin_bit_cast(unsigned, f);
    u = u + 0x7FFFu + ((u >> 16) & 1u);
    return (unsigned short)(u >> 16);
}
__device__ __forceinline__ float bf2f(unsigned short s) {
    return __builtin_bit_cast(float, ((unsigned)s) << 16);
}
// packed RNE f32x2 -> bf16x2 (v_cvt_pk_bf16_f32); low16 = a, high16 = b
__device__ __forceinline__ unsigned pk_bf16(float a, float b) {
    float2 t; t.x = a; t.y = b;
    __hip_bfloat162 p = __float22bfloat162_rn(t);
    unsigned u;
    __builtin_memcpy(&u, &p, sizeof(u));
    return u;
}

struct LstmState {
    float c[4];
    float hlast[4];
};

__global__ __attribute__((amdgpu_flat_work_group_size(256, 256),
                          amdgpu_waves_per_eu(1, 1)))
void lstm_mfma_kernel(
    const float* __restrict__ x,      // [B, 1, T]
    const float* __restrict__ W_ih,   // [256, 1]
    const float* __restrict__ W_hh,   // [256, 64]
    const float* __restrict__ b_ih,   // [256]
    const float* __restrict__ b_hh,   // [256]
    const float* __restrict__ fc1_w,  // [64, 64]
    const float* __restrict__ fc1_b,  // [64]
    const float* __restrict__ fc2_w,  // [10, 64]
    const float* __restrict__ fc2_b,  // [10]
    float* __restrict__ out)          // [B, 10]
{
    const int tid  = threadIdx.x;
    const int lane = tid & 63;
    const int w    = tid >> 6;        // wave id = unit group
    const int quad = lane >> 4;
    const int col  = lane & 15;
    const int row0 = blockIdx.x * 16; // batch rows [row0, row0+16)

    __shared__ short whi[32 * 512];        // 32 KB: W_hh hi fragments
    __shared__ short wlo[32 * 512];        // 32 KB: W_hh lo fragments
    __shared__ short abuf[2][2048];        // A frags double buffer (hi|lo)
    __shared__ __align__(16) float xlds[XCH][16];  // 8 KB x chunk [t_local][row]
    __shared__ float hf[16][HID + 1];
    __shared__ float r1buf[16][HID + 1];

    // ---- setup: convert W_hh f32 -> bf16 hi/lo fragments in LDS ----
    for (int idx = tid; idx < 256 * 64; idx += 256) {
        int r_ = idx >> 6;            // gate-major row 0..255
        int k  = idx & 63;
        float f = W_hh[r_ * 64 + k];
        unsigned short hi = f2bf(f);
        unsigned short lo = f2bf(f - bf2f(hi));
        int g = r_ >> 6, u = r_ & 63;
        int w_ = u >> 4, n = u & 15;
        int kt = k >> 5, q = (k & 31) >> 3, j = k & 7;
        int off = (((w_ * 4 + g) * 2 + kt) * 64 + (q * 16 + n)) * 8 + j;
        whi[off] = (short)hi;
        wlo[off] = (short)lo;
    }
    for (int idx = tid; idx < 2048; idx += 256) abuf[0][idx] = 0;  // h0 = 0
    __syncthreads();

    // ---- per-lane constants ----
    const int unit = w * 16 + col;
    float wih_l[4];
    f32x4 biasv[4];
    f32x4 zerov = {0.f, 0.f, 0.f, 0.f};
    #pragma unroll
    for (int g = 0; g < 4; ++g) {
        wih_l[g] = W_ih[g * HID + unit];
        float bs = b_ih[g * HID + unit] + b_hh[g * HID + unit];
        #pragma unroll
        for (int r = 0; r < 4; ++r) biasv[g][r] = bs;
    }

    // B fragments -> registers (64 VGPRs), lane-contiguous 16B reads.
    bf16x8 Bhi[4][2], Blo[4][2];
    #pragma unroll
    for (int g = 0; g < 4; ++g) {
        #pragma unroll
        for (int kt = 0; kt < 2; ++kt) {
            int off = (((w * 4 + g) * 2 + kt) * 64 + lane) * 8;
            Bhi[g][kt] = *(const bf16x8*)&whi[off];
            Blo[g][kt] = *(const bf16x8*)&wlo[off];
            asm volatile("" : "+v"(Bhi[g][kt]));
            asm volatile("" : "+v"(Blo[g][kt]));
        }
    }

    const float* xbase = x + (size_t)row0 * T_STEPS;
    const int xl_row = tid >> 4;
    const int xl_tb  = (tid & 15) * 8;

    LstmState st;
    #pragma unroll
    for (int r = 0; r < 4; ++r) { st.c[r] = 0.f; st.hlast[r] = 0.f; }

    // invariant LDS coords
    const int ard  = lane * 8;                                    // A-read slot base (shorts)
    const int awr  = ((w >> 1) * 64 + ((w & 1) * 2 + (col >> 3)) * 16 + quad * 4) * 8 + (col & 7);

    // one step; CUR = which abuf is read (compile-time)
    auto step = [&](auto cur_c, int tl) __attribute__((always_inline)) {
        constexpr int CUR = decltype(cur_c)::value;
        constexpr int NXT = CUR ^ 1;

        // x for this lane's 4 rows (consumed post-MFMA)
        f32x4 xv = *(const f32x4*)&xlds[tl][quad * 4];

        // A fragments (lane-contiguous b128, conflict-free, invariant addrs)
        bf16x8 Ahi0 = *(const bf16x8*)&abuf[CUR][ard];
        bf16x8 Ahi1 = *(const bf16x8*)&abuf[CUR][512 + ard];
        bf16x8 Alo0 = *(const bf16x8*)&abuf[CUR][1024 + ard];
        bf16x8 Alo1 = *(const bf16x8*)&abuf[CUR][1536 + ard];

        // kt-split accumulators, bias/zero as MFMA C operand (no init movs)
        f32x4 accA[4], accB[4];
        #pragma unroll
        for (int g = 0; g < 4; ++g) {
            accA[g] = __builtin_amdgcn_mfma_f32_16x16x32_bf16(Ahi0, Bhi[g][0], biasv[g], 0, 0, 0);
            accB[g] = __builtin_amdgcn_mfma_f32_16x16x32_bf16(Ahi1, Bhi[g][1], zerov, 0, 0, 0);
        }
        #pragma unroll
        for (int g = 0; g < 4; ++g) {
            accA[g] = __builtin_amdgcn_mfma_f32_16x16x32_bf16(Alo0, Bhi[g][0], accA[g], 0, 0, 0);
            accB[g] = __builtin_amdgcn_mfma_f32_16x16x32_bf16(Alo1, Bhi[g][1], accB[g], 0, 0, 0);
        }
        #pragma unroll
        for (int g = 0; g < 4; ++g) {
            accA[g] = __builtin_amdgcn_mfma_f32_16x16x32_bf16(Ahi0, Blo[g][0], accA[g], 0, 0, 0);
            accB[g] = __builtin_amdgcn_mfma_f32_16x16x32_bf16(Ahi1, Blo[g][1], accB[g], 0, 0, 0);
        }

        // LSTM update, 4 rows
        float h[4];
        #pragma unroll
        for (int r = 0; r < 4; ++r) {
            float a0 = fmaf(xv[r], wih_l[0], accA[0][r] + accB[0][r]);
            float a1 = fmaf(xv[r], wih_l[1], accA[1][r] + accB[1][r]);
            float a2 = fmaf(xv[r], wih_l[2], accA[2][r] + accB[2][r]);
            float a3 = fmaf(xv[r], wih_l[3], accA[3][r] + accB[3][r]);
            float ig = sigm(a0);
            float fg = sigm(a1);
            float gg = tanh_f(a2);
            float og = sigm(a3);
            st.c[r] = fmaf(fg, st.c[r], ig * gg);
            h[r] = og * tanh_f(st.c[r]);
            st.hlast[r] = h[r];
        }

        // packed hi/lo split; writes at invariant addr + imm offsets
        unsigned up01 = pk_bf16(h[0], h[1]);
        unsigned up23 = pk_bf16(h[2], h[3]);
        float l0 = h[0] - __builtin_bit_cast(float, up01 << 16);
        float l1 = h[1] - __builtin_bit_cast(float, up01 & 0xFFFF0000u);
        float l2 = h[2] - __builtin_bit_cast(float, up23 << 16);
        float l3 = h[3] - __builtin_bit_cast(float, up23 & 0xFFFF0000u);
        unsigned lp01 = pk_bf16(l0, l1);
        unsigned lp23 = pk_bf16(l2, l3);

        short* wr = &abuf[NXT][awr];
        wr[0]  = (short)(up01 & 0xFFFFu);
        wr[8]  = (short)(up01 >> 16);
        wr[16] = (short)(up23 & 0xFFFFu);
        wr[24] = (short)(up23 >> 16);
        wr[1024 + 0]  = (short)(lp01 & 0xFFFFu);
        wr[1024 + 8]  = (short)(lp01 >> 16);
        wr[1024 + 16] = (short)(lp23 & 0xFFFFu);
        wr[1024 + 24] = (short)(lp23 >> 16);

        __syncthreads();
    };

    #pragma unroll 1
    for (int tc = 0; tc < T_STEPS; tc += 2) {
        const int tl = tc & (XCH - 1);
        if (tl == 0) {
            // refill x chunk (prev end-of-step barrier => old chunk consumed)
            const float* src = xbase + (size_t)xl_row * T_STEPS + tc + xl_tb;
            float4 v0 = *(const float4*)(src);
            float4 v1 = *(const float4*)(src + 4);
            xlds[xl_tb + 0][xl_row] = v0.x;
            xlds[xl_tb + 1][xl_row] = v0.y;
            xlds[xl_tb + 2][xl_row] = v0.z;
            xlds[xl_tb + 3][xl_row] = v0.w;
            xlds[xl_tb + 4][xl_row] = v1.x;
            xlds[xl_tb + 5][xl_row] = v1.y;
            xlds[xl_tb + 6][xl_row] = v1.z;
            xlds[xl_tb + 7][xl_row] = v1.w;
            __syncthreads();
        }
        step(std::integral_constant<int, 0>{}, tl);      // reads abuf[0], writes abuf[1]
        step(std::integral_constant<int, 1>{}, tl + 1);  // reads abuf[1], writes abuf[0]
    }

    // ---- epilogue: fc1 (relu) + fc2, once per block ----
    #pragma unroll
    for (int r = 0; r < 4; ++r) hf[quad * 4 + r][unit] = st.hlast[r];
    __syncthreads();

    {
        int m_ = tid & 15, ug = tid >> 4;  // thread: row m_, units ug*4..+3
        #pragma unroll
        for (int uu = 0; uu < 4; ++uu) {
            int u = ug * 4 + uu;
            float s = fc1_b[u];
            const float4* wrow = (const float4*)(fc1_w + u * HID);
            #pragma unroll
            for (int j4 = 0; j4 < HID / 4; ++j4) {
                float4 wv = wrow[j4];
                s = fmaf(hf[m_][j4 * 4 + 0], wv.x, s);
                s = fmaf(hf[m_][j4 * 4 + 1], wv.y, s);
                s = fmaf(hf[m_][j4 * 4 + 2], wv.z, s);
                s = fmaf(hf[m_][j4 * 4 + 3], wv.w, s);
            }
            r1buf[m_][u] = fmaxf(s, 0.0f);
        }
    }
    __syncthreads();

    if (tid < 16 * NCLS) {
        int m = tid / NCLS, cls = tid % NCLS;
        float s = fc2_b[cls];
        const float* w2 = fc2_w + cls * HID;
        #pragma unroll
        for (int j = 0; j < HID; ++j) s = fmaf(r1buf[m][j], w2[j], s);
        out[(size_t)(row0 + m) * NCLS + cls] = s;
    }
}

extern "C" void kernel_launch(void* const* d_in, const int* in_sizes, int n_in,
                              void* d_out, int out_size, void* d_ws, size_t ws_size,
                              hipStream_t stream) {
    const float* x     = (const float*)d_in[0];
    const float* W_ih  = (const float*)d_in[1];
    const float* W_hh  = (const float*)d_in[2];
    const float* b_ih  = (const float*)d_in[3];
    const float* b_hh  = (const float*)d_in[4];
    const float* fc1_w = (const float*)d_in[5];
    const float* fc1_b = (const float*)d_in[6];
    const float* fc2_w = (const float*)d_in[7];
    const float* fc2_b = (const float*)d_in[8];
    float* out = (float*)d_out;

    dim3 grid(64);    // 1024 rows / 16 rows per block
    dim3 block(256);  // 4 waves
    lstm_mfma_kernel<<<grid, block, 0, stream>>>(x, W_ih, W_hh, b_ih, b_hh,
                                                 fc1_w, fc1_b, fc2_w, fc2_b, out);
}

// Round 9
// 1279.849 us; speedup vs baseline: 1.1588x; 1.1588x over previous
//
#include <hip/hip_runtime.h>
#include <hip/hip_bf16.h>
#include <type_traits>

// LSTMNet: B=1024, T=2048, H=64, NC=10, input_size=1.
// MFMA (16x16x32 bf16) split-bf16 (hi+lo) fp32 emulation.
// R9 restructure: 128 blocks x 512 thr (8 waves); block owns 8 batch rows.
//   Compute phase: wave w owns gate (w>>1), unit-half 32*(w&1): 2 N-tiles
//     -> 12 MFMAs/wave; gate outputs -> gbuf[m][u][4] (b128-readable).
//   Update phase: tid = cell (m=tid>>6, u=lane) -> 1 cell/lane -> only 10
//     trans wave-instrs (R8 had 40: cells/lane was pinned at 4 by C-layout).
//   2 barriers/step; 2 waves/SIMD overlap stalls; 128 CUs active (was 64).
// R8 post-mortem: VALU busy ~960cyc/step on active CUs, dominated by
// quarter-rate transcendentals x 4 cells/lane. This spreads the activation
// work to 1 cell/lane and the MFMA/N-work over 8 waves.

#define T_STEPS 2048
#define HID 64
#define NCLS 10
#define XCH 128   // x chunk length (steps)
#define ROWS 8    // batch rows per block

typedef short bf16x8 __attribute__((ext_vector_type(8)));
typedef float f32x4 __attribute__((ext_vector_type(4)));

__device__ __forceinline__ float sigm(float x) {
    float e = __builtin_amdgcn_exp2f(-1.4426950408889634f * x);
    return __builtin_amdgcn_rcpf(1.0f + e);
}
__device__ __forceinline__ float tanh_f(float x) {
    float e = __builtin_amdgcn_exp2f(-2.8853900817779268f * x);
    return fmaf(2.0f, __builtin_amdgcn_rcpf(1.0f + e), -1.0f);
}
__device__ __forceinline__ unsigned short f2bf(float f) {  // RNE f32->bf16
    unsigned u = __builtin_bit_cast(unsigned, f);
    u = u + 0x7FFFu + ((u >> 16) & 1u);
    return (unsigned short)(u >> 16);
}
__device__ __forceinline__ float bf2f(unsigned short s) {
    return __builtin_bit_cast(float, ((unsigned)s) << 16);
}

__global__ __attribute__((amdgpu_flat_work_group_size(512, 512),
                          amdgpu_waves_per_eu(2, 2)))
void lstm_mfma_kernel(
    const float* __restrict__ x,      // [B, 1, T]
    const float* __restrict__ W_ih,   // [256, 1]
    const float* __restrict__ W_hh,   // [256, 64]
    const float* __restrict__ b_ih,   // [256]
    const float* __restrict__ b_hh,   // [256]
    const float* __restrict__ fc1_w,  // [64, 64]
    const float* __restrict__ fc1_b,  // [64]
    const float* __restrict__ fc2_w,  // [10, 64]
    const float* __restrict__ fc2_b,  // [10]
    float* __restrict__ out)          // [B, 10]
{
    const int tid  = threadIdx.x;
    const int lane = tid & 63;
    const int w    = tid >> 6;        // wave id
    const int quad = lane >> 4;
    const int col  = lane & 15;
    const int row0 = blockIdx.x * ROWS;

    __shared__ short whi[32 * 512];          // 32 KB: W_hh hi fragments
    __shared__ short wlo[32 * 512];          // 32 KB: W_hh lo fragments
    __shared__ short abuf[2][2048];          // A frags double buffer (hi|lo)
    __shared__ float gbuf[ROWS][HID][4];     // 8 KB: gates [m][u][g]
    __shared__ __align__(16) float xlds[ROWS][XCH + 4];  // x chunk [row][t_local]
    __shared__ float hf[ROWS][HID + 1];
    __shared__ float r1buf[ROWS][HID + 1];

    // ---- setup: W_hh f32 -> bf16 hi/lo fragments in LDS (R5-verified layout)
    // tile id t = (u>>4)*4 + g; frag fid = t*2+kt; slot = (kq*16 + n)*8 + j
    for (int idx = tid; idx < 256 * 64; idx += 512) {
        int r_ = idx >> 6;            // gate-major row 0..255
        int k  = idx & 63;
        float f = W_hh[r_ * 64 + k];
        unsigned short hi = f2bf(f);
        unsigned short lo = f2bf(f - bf2f(hi));
        int g = r_ >> 6, u = r_ & 63;
        int u4 = u >> 4, n = u & 15;
        int kt = k >> 5, kq = (k & 31) >> 3, j = k & 7;
        int off = (((u4 * 4 + g) * 2 + kt) * 64 + (kq * 16 + n)) * 8 + j;
        whi[off] = (short)hi;
        wlo[off] = (short)lo;
    }
    // zero BOTH A buffers (rows 8..15 are never written -> must stay zero)
    for (int idx = tid; idx < 4096; idx += 512) ((short*)abuf)[idx] = 0;
    __syncthreads();

    // ---- compute-phase constants: wave w -> gate g_w, unit-16-blocks u4a..+1
    const int g_w  = w >> 1;
    const int u4a  = (w & 1) * 2;

    bf16x8 Bhi[2][2], Blo[2][2];
    f32x4 biasC[2];
    f32x4 zerov = {0.f, 0.f, 0.f, 0.f};
    #pragma unroll
    for (int tt = 0; tt < 2; ++tt) {
        int t_ = (u4a + tt) * 4 + g_w;
        #pragma unroll
        for (int kt = 0; kt < 2; ++kt) {
            int off = ((t_ * 2 + kt) * 64 + lane) * 8;
            Bhi[tt][kt] = *(const bf16x8*)&whi[off];
            Blo[tt][kt] = *(const bf16x8*)&wlo[off];
            asm volatile("" : "+v"(Bhi[tt][kt]));
            asm volatile("" : "+v"(Blo[tt][kt]));
        }
        int u = (u4a + tt) * 16 + col;
        float bs = b_ih[g_w * HID + u] + b_hh[g_w * HID + u];
        #pragma unroll
        for (int r = 0; r < 4; ++r) biasC[tt][r] = bs;
    }

    // ---- update-phase constants: this thread owns cell (m = w, u = lane)
    float wih_u[4];
    #pragma unroll
    for (int g = 0; g < 4; ++g) wih_u[g] = W_ih[g * HID + lane];

    const float* xbase = x + (size_t)row0 * T_STEPS;

    float cc = 0.f, hl = 0.f;   // cell state for (row w, unit lane)

    // invariant LDS coords
    const int ard = lane * 8;   // A-read slot base (shorts)
    // h-writer A-slot for (m = w, k = lane): kt=lane>>5, kq=(lane>>3)&3, j=lane&7
    const int awr = ((lane >> 5) * 64 + ((lane >> 3) & 3) * 16 + w) * 8 + (lane & 7);

    auto step = [&](auto cur_c, int tl) __attribute__((always_inline)) {
        constexpr int CUR = decltype(cur_c)::value;
        constexpr int NXT = CUR ^ 1;

        // ---- compute phase: 2 N-tiles, 12 MFMAs ----
        bf16x8 Ahi0 = *(const bf16x8*)&abuf[CUR][ard];
        bf16x8 Ahi1 = *(const bf16x8*)&abuf[CUR][512 + ard];
        bf16x8 Alo0 = *(const bf16x8*)&abuf[CUR][1024 + ard];
        bf16x8 Alo1 = *(const bf16x8*)&abuf[CUR][1536 + ard];

        f32x4 accA[2], accB[2];
        #pragma unroll
        for (int tt = 0; tt < 2; ++tt) {
            accA[tt] = __builtin_amdgcn_mfma_f32_16x16x32_bf16(Ahi0, Bhi[tt][0], biasC[tt], 0, 0, 0);
            accB[tt] = __builtin_amdgcn_mfma_f32_16x16x32_bf16(Ahi1, Bhi[tt][1], zerov, 0, 0, 0);
        }
        #pragma unroll
        for (int tt = 0; tt < 2; ++tt) {
            accA[tt] = __builtin_amdgcn_mfma_f32_16x16x32_bf16(Alo0, Bhi[tt][0], accA[tt], 0, 0, 0);
            accB[tt] = __builtin_amdgcn_mfma_f32_16x16x32_bf16(Alo1, Bhi[tt][1], accB[tt], 0, 0, 0);
        }
        #pragma unroll
        for (int tt = 0; tt < 2; ++tt) {
            accA[tt] = __builtin_amdgcn_mfma_f32_16x16x32_bf16(Ahi0, Blo[tt][0], accA[tt], 0, 0, 0);
            accB[tt] = __builtin_amdgcn_mfma_f32_16x16x32_bf16(Ahi1, Blo[tt][1], accB[tt], 0, 0, 0);
        }

        // write gates for valid rows (m = quad*4+r < 8 -> quads 0,1)
        if (quad < 2) {
            #pragma unroll
            for (int tt = 0; tt < 2; ++tt) {
                int u = (u4a + tt) * 16 + col;
                #pragma unroll
                for (int r = 0; r < 4; ++r) {
                    gbuf[quad * 4 + r][u][g_w] = accA[tt][r] + accB[tt][r];
                }
            }
        }
        __syncthreads();

        // ---- update phase: 1 cell per thread (m = w, u = lane) ----
        f32x4 gv = *(const f32x4*)&gbuf[w][lane][0];  // i,f,g,o (bias included)
        float xv = xlds[w][tl];                        // wave-uniform broadcast

        float a0 = fmaf(xv, wih_u[0], gv[0]);
        float a1 = fmaf(xv, wih_u[1], gv[1]);
        float a2 = fmaf(xv, wih_u[2], gv[2]);
        float a3 = fmaf(xv, wih_u[3], gv[3]);
        float ig = sigm(a0);
        float fg = sigm(a1);
        float gg = tanh_f(a2);
        float og = sigm(a3);
        cc = fmaf(fg, cc, ig * gg);
        float h = og * tanh_f(cc);
        hl = h;

        unsigned short hh = f2bf(h);
        unsigned short hlo = f2bf(h - bf2f(hh));
        abuf[NXT][awr]        = (short)hh;
        abuf[NXT][1024 + awr] = (short)hlo;

        __syncthreads();
    };

    #pragma unroll 1
    for (int tc = 0; tc < T_STEPS; tc += 2) {
        const int tl = tc & (XCH - 1);
        if (tl == 0) {
            // refill x chunk (prev barrier => old chunk fully consumed)
            if (tid < 128) {
                int xr = tid >> 4, tb = (tid & 15) * 8;
                const float* src = xbase + (size_t)xr * T_STEPS + tc + tb;
                float4 v0 = *(const float4*)(src);
                float4 v1 = *(const float4*)(src + 4);
                *(float4*)&xlds[xr][tb]     = v0;
                *(float4*)&xlds[xr][tb + 4] = v1;
            }
            __syncthreads();
        }
        step(std::integral_constant<int, 0>{}, tl);      // reads abuf[0], writes abuf[1]
        step(std::integral_constant<int, 1>{}, tl + 1);  // reads abuf[1], writes abuf[0]
    }

    // ---- epilogue: fc1 (relu) + fc2 ----
    hf[w][lane] = hl;
    __syncthreads();

    {
        // thread -> output (m = w, unit = lane)
        float s = fc1_b[lane];
        const float4* wrow = (const float4*)(fc1_w + lane * HID);
        #pragma unroll
        for (int j4 = 0; j4 < HID / 4; ++j4) {
            float4 wv = wrow[j4];
            s = fmaf(hf[w][j4 * 4 + 0], wv.x, s);
            s = fmaf(hf[w][j4 * 4 + 1], wv.y, s);
            s = fmaf(hf[w][j4 * 4 + 2], wv.z, s);
            s = fmaf(hf[w][j4 * 4 + 3], wv.w, s);
        }
        r1buf[w][lane] = fmaxf(s, 0.0f);
    }
    __syncthreads();

    if (tid < ROWS * NCLS) {
        int m = tid / NCLS, cls = tid % NCLS;
        float s = fc2_b[cls];
        const float* w2 = fc2_w + cls * HID;
        #pragma unroll
        for (int j = 0; j < HID; ++j) s = fmaf(r1buf[m][j], w2[j], s);
        out[(size_t)(row0 + m) * NCLS + cls] = s;
    }
}

extern "C" void kernel_launch(void* const* d_in, const int* in_sizes, int n_in,
                              void* d_out, int out_size, void* d_ws, size_t ws_size,
                              hipStream_t stream) {
    const float* x     = (const float*)d_in[0];
    const float* W_ih  = (const float*)d_in[1];
    const float* W_hh  = (const float*)d_in[2];
    const float* b_ih  = (const float*)d_in[3];
    const float* b_hh  = (const float*)d_in[4];
    const float* fc1_w = (const float*)d_in[5];
    const float* fc1_b = (const float*)d_in[6];
    const float* fc2_w = (const float*)d_in[7];
    const float* fc2_b = (const float*)d_in[8];
    float* out = (float*)d_out;

    dim3 grid(128);   // 1024 rows / 8 rows per block
    dim3 block(512);  // 8 waves
    lstm_mfma_kernel<<<grid, block, 0, stream>>>(x, W_ih, W_hh, b_ih, b_hh,
                                                 fc1_w, fc1_b, fc2_w, fc2_b, out);
}